// Round 1
// baseline (660.988 us; speedup 1.0000x reference)
//
#include <hip/hip_runtime.h>

// Problem constants (B=2, H=W=512, 21 classes, 11x11 window, 4x blur).
// H,W divisible by BLUR=4 -> pad=(0,0): avg-pool is exact 4x4 mean, crop is identity.
#define NCH 21
#define HH 512
#define WW 512
#define HP 128
#define WP 128
#define HWF (1 << 18)   // 512*512
#define HWP (1 << 14)   // 128*128
#define KS 11
#define KK 121
#define KPAD 5

// ---------------- unary = conv3x3(x, w) + b ----------------
__global__ __launch_bounds__(256) void k_conv(const float* __restrict__ x,
                                              const float* __restrict__ w,
                                              const float* __restrict__ bias,
                                              float* __restrict__ unary) {
    int idx = blockIdx.x * 256 + threadIdx.x;   // 0..262143 pixel index
    int o = blockIdx.y;                          // 0..20
    int b = blockIdx.z;                          // 0..1
    int y = idx >> 9, xx = idx & 511;
    float acc = bias[o];
    const float* wp = w + o * 27;
#pragma unroll
    for (int i = 0; i < 3; ++i) {
        const float* xp = x + (((size_t)(b * 3 + i)) << 18);
#pragma unroll
        for (int ky = 0; ky < 3; ++ky) {
            int yy = y + ky - 1;
            if ((unsigned)yy >= 512u) continue;
#pragma unroll
            for (int kx = 0; kx < 3; ++kx) {
                int xc = xx + kx - 1;
                if ((unsigned)xc >= 512u) continue;
                acc += xp[(yy << 9) + xc] * wp[i * 9 + ky * 3 + kx];
            }
        }
    }
    unary[(((size_t)(b * NCH + o)) << 18) + idx] = acc;
}

// ---------------- pooled RGB (raw, scale applied later) ----------------
__global__ __launch_bounds__(256) void k_pool_rgb(const float* __restrict__ x,
                                                  float* __restrict__ prgb) {
    int idx = blockIdx.x * 256 + threadIdx.x;   // 0..98303  [b][3][128][128]
    int p = idx & (HWP - 1);
    int ch = (idx >> 14) % 3;
    int b = idx / (3 * HWP);
    int py = p >> 7, px = p & 127;
    const float* xp = x + (((size_t)(b * 3 + ch)) << 18);
    float s = 0.f;
#pragma unroll
    for (int r = 0; r < 4; ++r) {
        const float4 v = *(const float4*)(xp + (((4 * py + r) << 9) + 4 * px));
        s += v.x + v.y + v.z + v.w;
    }
    prgb[idx] = s * 0.0625f;
}

// ---------------- combined pairwise kernel kc = pw0*exp(-.5 s_bilateral) + pw1*exp(-.5 s_spatial) ----------------
__global__ __launch_bounds__(256) void k_build_kc(const float* __restrict__ prgb,
                                                  const float* __restrict__ pw,
                                                  float* __restrict__ kc) {
    int idx = blockIdx.x * 256 + threadIdx.x;   // 0..32767  [b][128][128]
    int p = idx & (HWP - 1);
    int b = idx >> 14;
    int py = p >> 7, px = p & 127;
    float pw0 = pw[0], pw1 = pw[1];

    // own pooled features (yx analytic; rgb from pooled planes, /13)
    const float inv13 = 1.0f / 13.0f;
    float fy = (4.f * py + 1.5f) * (1.0f / 80.0f);
    float fx = (4.f * px + 1.5f) * (1.0f / 80.0f);
    float r0 = prgb[(b * 3 + 0) * HWP + p] * inv13;
    float g0 = prgb[(b * 3 + 1) * HWP + p] * inv13;
    float b0 = prgb[(b * 3 + 2) * HWP + p] * inv13;
    float sy = (4.f * py + 1.5f) * (1.0f / 3.0f);
    float sx = (4.f * px + 1.5f) * (1.0f / 3.0f);

    float oob1 = fy * fy + fx * fx + r0 * r0 + g0 * g0 + b0 * b0;  // patch=0 case
    float oob2 = sy * sy + sx * sx;

    for (int dy = 0; dy < KS; ++dy) {
        int ny = py + dy - KPAD;
        bool yin = (unsigned)ny < (unsigned)HP;
        for (int dx = 0; dx < KS; ++dx) {
            int nx = px + dx - KPAD;
            float s1, s2;
            if (yin && (unsigned)nx < (unsigned)WP) {
                int np = (ny << 7) + nx;
                float r2 = prgb[(b * 3 + 0) * HWP + np] * inv13;
                float g2 = prgb[(b * 3 + 1) * HWP + np] * inv13;
                float b2 = prgb[(b * 3 + 2) * HWP + np] * inv13;
                float dya = fy - (4.f * ny + 1.5f) * (1.0f / 80.0f);
                float dxa = fx - (4.f * nx + 1.5f) * (1.0f / 80.0f);
                float dr = r0 - r2, dg = g0 - g2, db = b0 - b2;
                s1 = dya * dya + dxa * dxa + dr * dr + dg * dg + db * db;
                float dys = sy - (4.f * ny + 1.5f) * (1.0f / 3.0f);
                float dxs = sx - (4.f * nx + 1.5f) * (1.0f / 3.0f);
                s2 = dys * dys + dxs * dxs;
            } else {
                s1 = oob1;
                s2 = oob2;
            }
            float k = pw0 * __expf(-0.5f * s1) + pw1 * __expf(-0.5f * s2);
            kc[(((size_t)(b * KK + dy * KS + dx)) << 14) + p] = k;
        }
    }
}

// ---------------- fused softmax(21ch) + 4x4 avg pool -> Qb ----------------
// 16 lanes per pooled pixel (one per sub-pixel); shfl_xor width-16 reduce.
__global__ __launch_bounds__(256) void k_softmax_pool(const float* __restrict__ logq,
                                                      float* __restrict__ qb) {
    int t = blockIdx.x * 256 + threadIdx.x;     // 0..524287
    int sub = t & 15;
    int pp = t >> 4;                            // pooled idx 0..32767
    int px = pp & 127, py = (pp >> 7) & 127, b = pp >> 14;
    int r = sub >> 2, i2 = sub & 3;
    int y = 4 * py + r, x = 4 * px + i2;
    int pix = (y << 9) + x;
    const float* sp = logq + (((size_t)(b * NCH)) << 18);

    float v[NCH];
#pragma unroll
    for (int c = 0; c < NCH; ++c) v[c] = sp[(c << 18) + pix];
    float m = v[0];
#pragma unroll
    for (int c = 1; c < NCH; ++c) m = fmaxf(m, v[c]);
    float s = 0.f;
#pragma unroll
    for (int c = 0; c < NCH; ++c) { v[c] = __expf(v[c] - m); s += v[c]; }
    float inv = 1.0f / s;
#pragma unroll
    for (int c = 0; c < NCH; ++c) {
        float q = v[c] * inv;
        q += __shfl_xor(q, 1, 16);
        q += __shfl_xor(q, 2, 16);
        q += __shfl_xor(q, 4, 16);
        q += __shfl_xor(q, 8, 16);
        if (sub == 0) qb[(((size_t)(b * NCH + c)) << 14) + (py << 7) + px] = q * 0.0625f;
    }
}

// ---------------- pac message: msg[c] = sum_j kc[j] * Qb[c, neighbor(j)] ----------------
__global__ __launch_bounds__(256) void k_pac(const float* __restrict__ qb,
                                             const float* __restrict__ kc,
                                             float* __restrict__ msgc) {
    int idx = blockIdx.x * 256 + threadIdx.x;   // 0..688127  [b][21][128][128]
    int p = idx & (HWP - 1);
    int px = p & 127, py = p >> 7;
    int t = idx >> 14;                          // 0..41
    int b = (t >= NCH) ? 1 : 0;
    int c = t - NCH * b;
    const float* q = qb + (((size_t)(b * NCH + c)) << 14);
    const float* kp = kc + (((size_t)(b * KK)) << 14) + p;
    float acc = 0.f;
#pragma unroll
    for (int dy = 0; dy < KS; ++dy) {
        int ny = py + dy - KPAD;
        if ((unsigned)ny >= (unsigned)HP) continue;
        const float* qrow = q + (ny << 7);
        int jb = dy * KS;
#pragma unroll
        for (int dx = 0; dx < KS; ++dx) {
            int nx = px + dx - KPAD;
            if ((unsigned)nx >= (unsigned)WP) continue;
            acc += kp[((size_t)(jb + dx)) << 14] * qrow[nx];
        }
    }
    msgc[idx] = acc;
}

// ---------------- fused bilinear x4 upsample + uw*unary + msg -> logQ (d_out) ----------------
__global__ __launch_bounds__(256) void k_upcombine(const float* __restrict__ unary,
                                                   const float* __restrict__ msgc,
                                                   const float* __restrict__ uwp,
                                                   float* __restrict__ out) {
    int idx = blockIdx.x * 256 + threadIdx.x;   // 0..11010047 [b][21][512][512]
    float uw = uwp[0];
    int x = idx & 511, y = (idx >> 9) & 511;
    int t = idx >> 18;                          // b*21+c, 0..41

    float syf = fminf(fmaxf(y * 0.25f - 0.375f, 0.0f), 127.0f);
    int y0 = (int)syf;
    float fy = syf - y0;
    int y1 = min(y0 + 1, 127);
    float sxf = fminf(fmaxf(x * 0.25f - 0.375f, 0.0f), 127.0f);
    int x0 = (int)sxf;
    float fx = sxf - x0;
    int x1 = min(x0 + 1, 127);

    const float* mp = msgc + (((size_t)t) << 14);
    float v00 = mp[(y0 << 7) + x0];
    float v01 = mp[(y0 << 7) + x1];
    float v10 = mp[(y1 << 7) + x0];
    float v11 = mp[(y1 << 7) + x1];
    float a = v00 + (v10 - v00) * fy;   // y-interp at x0
    float bl = v01 + (v11 - v01) * fy;  // y-interp at x1
    float val = a + (bl - a) * fx;

    out[idx] = uw * unary[idx] + val;
}

extern "C" void kernel_launch(void* const* d_in, const int* in_sizes, int n_in,
                              void* d_out, int out_size, void* d_ws, size_t ws_size,
                              hipStream_t stream) {
    const float* x  = (const float*)d_in[0];
    const float* wb = (const float*)d_in[1];
    const float* bb = (const float*)d_in[2];
    const float* uw = (const float*)d_in[3];
    const float* pw = (const float*)d_in[4];
    float* out = (float*)d_out;

    float* ws    = (float*)d_ws;
    float* unary = ws;                    // 2*21*512*512 = 11,010,048
    float* kc    = unary + 11010048;      // 2*121*128*128 = 3,964,928
    float* qb    = kc + 3964928;          // 2*21*128*128 = 688,128
    float* msgc  = qb + 688128;           // 688,128
    float* prgb  = msgc + 688128;         // 2*3*128*128 = 98,304
    // total ~65.8 MB of workspace

    k_conv<<<dim3(1024, NCH, 2), 256, 0, stream>>>(x, wb, bb, unary);
    k_pool_rgb<<<384, 256, 0, stream>>>(x, prgb);
    k_build_kc<<<128, 256, 0, stream>>>(prgb, pw, kc);

    const float* logq = unary;            // logQ starts as unary
    for (int s = 0; s < 5; ++s) {
        k_softmax_pool<<<2048, 256, 0, stream>>>(logq, qb);
        k_pac<<<2688, 256, 0, stream>>>(qb, kc, msgc);
        k_upcombine<<<43008, 256, 0, stream>>>(unary, msgc, uw, out);
        logq = out;
    }
}

// Round 3
// 412.111 us; speedup vs baseline: 1.6039x; 1.6039x over previous
//
#include <hip/hip_runtime.h>

// B=2, H=W=512, 21 classes, 11x11 window, 4x blur. H,W % 4 == 0 -> pad=(0,0),
// avg-pool is exact 4x4 mean, post-upsample crop is identity.
#define NCH 21
#define HWF (1 << 18)   // 512*512
#define HWP (1 << 14)   // 128*128
#define KS 11
#define KK 121
#define KPAD 5
#define QSTR 24         // padded per-pixel channel stride for transposed Q

// ---------------- unary = conv3x3(x,w)+b : thread = 4-px quad, all 21 outputs ----------------
__global__ __launch_bounds__(256) void k_conv(const float* __restrict__ x,
                                              const float* __restrict__ w,
                                              const float* __restrict__ bias,
                                              float* __restrict__ unary) {
    int idx = blockIdx.x * 256 + threadIdx.x;   // 0..131071  [b][512][128]
    int b = idx >> 16;
    int rem = idx & 65535;
    int y = rem >> 7;
    int xq = (rem & 127) << 2;                  // base x, multiple of 4

    // patch[ch][row][6] covers cols xq-1 .. xq+4 (zero-padded)
    float p[3][3][6];
#pragma unroll
    for (int ch = 0; ch < 3; ++ch) {
        const float* xp = x + (((size_t)(b * 3 + ch)) << 18);
#pragma unroll
        for (int r = 0; r < 3; ++r) {
            int yy = y + r - 1;
            if ((unsigned)yy >= 512u) {
#pragma unroll
                for (int j = 0; j < 6; ++j) p[ch][r][j] = 0.f;
            } else {
                const float* row = xp + (yy << 9);
                float4 v = *(const float4*)(row + xq);
                p[ch][r][1] = v.x; p[ch][r][2] = v.y; p[ch][r][3] = v.z; p[ch][r][4] = v.w;
                p[ch][r][0] = (xq > 0) ? row[xq - 1] : 0.f;
                p[ch][r][5] = (xq + 4 < 512) ? row[xq + 4] : 0.f;
            }
        }
    }
    for (int o = 0; o < NCH; ++o) {
        const float* wp = w + o * 27;
        float bz = bias[o];
        float a0 = bz, a1 = bz, a2 = bz, a3 = bz;
#pragma unroll
        for (int ch = 0; ch < 3; ++ch)
#pragma unroll
            for (int r = 0; r < 3; ++r) {
                float w0 = wp[ch * 9 + r * 3 + 0];
                float w1 = wp[ch * 9 + r * 3 + 1];
                float w2 = wp[ch * 9 + r * 3 + 2];
                const float* pr = p[ch][r];
                a0 += w0 * pr[0] + w1 * pr[1] + w2 * pr[2];
                a1 += w0 * pr[1] + w1 * pr[2] + w2 * pr[3];
                a2 += w0 * pr[2] + w1 * pr[3] + w2 * pr[4];
                a3 += w0 * pr[3] + w1 * pr[4] + w2 * pr[5];
            }
        float4 ov = make_float4(a0, a1, a2, a3);
        *(float4*)(unary + (((size_t)(b * NCH + o)) << 18) + (y << 9) + xq) = ov;
    }
}

// ---------------- pooled RGB ----------------
__global__ __launch_bounds__(256) void k_pool_rgb(const float* __restrict__ x,
                                                  float* __restrict__ prgb) {
    int idx = blockIdx.x * 256 + threadIdx.x;   // 0..98303  [b][3][128][128]
    int p = idx & (HWP - 1);
    int ch = (idx >> 14) % 3;
    int b = idx / (3 * HWP);
    int py = p >> 7, px = p & 127;
    const float* xp = x + (((size_t)(b * 3 + ch)) << 18);
    float s = 0.f;
#pragma unroll
    for (int r = 0; r < 4; ++r) {
        const float4 v = *(const float4*)(xp + (((4 * py + r) << 9) + 4 * px));
        s += v.x + v.y + v.z + v.w;
    }
    prgb[idx] = s * 0.0625f;
}

// ---------------- kc = pw0*exp(-.5 s_bil) + pw1*exp(-.5 s_spat), thread per (b,tap,pixel) ----------------
__global__ __launch_bounds__(256) void k_build_kc(const float* __restrict__ prgb,
                                                  const float* __restrict__ pw,
                                                  float* __restrict__ kc) {
    int idx = blockIdx.x * 256 + threadIdx.x;   // 0..(2*121*16384-1)  [b][j][p]
    int p = idx & (HWP - 1);
    int jj = idx >> 14;                          // 0..241
    int b = (jj >= KK) ? 1 : 0;
    int j = jj - KK * b;
    int dy = j / KS, dx = j - dy * KS;
    int py = p >> 7, px = p & 127;
    float pw0 = pw[0], pw1 = pw[1];

    const float inv13 = 1.0f / 13.0f;
    float fy = (4.f * py + 1.5f) * (1.0f / 80.0f);
    float fx = (4.f * px + 1.5f) * (1.0f / 80.0f);
    const float* pb = prgb + (size_t)b * 3 * HWP;
    float r0 = pb[p] * inv13;
    float g0 = pb[HWP + p] * inv13;
    float b0 = pb[2 * HWP + p] * inv13;
    float sy = (4.f * py + 1.5f) * (1.0f / 3.0f);
    float sx = (4.f * px + 1.5f) * (1.0f / 3.0f);

    int ny = py + dy - KPAD;
    int nx = px + dx - KPAD;
    float s1, s2;
    if ((unsigned)ny < 128u && (unsigned)nx < 128u) {
        int np = (ny << 7) + nx;
        float r2 = pb[np] * inv13;
        float g2 = pb[HWP + np] * inv13;
        float b2 = pb[2 * HWP + np] * inv13;
        float dya = fy - (4.f * ny + 1.5f) * (1.0f / 80.0f);
        float dxa = fx - (4.f * nx + 1.5f) * (1.0f / 80.0f);
        float dr = r0 - r2, dg = g0 - g2, db = b0 - b2;
        s1 = dya * dya + dxa * dxa + dr * dr + dg * dg + db * db;
        float dys = sy - (4.f * ny + 1.5f) * (1.0f / 3.0f);
        float dxs = sx - (4.f * nx + 1.5f) * (1.0f / 3.0f);
        s2 = dys * dys + dxs * dxs;
    } else {
        s1 = fy * fy + fx * fx + r0 * r0 + g0 * g0 + b0 * b0;  // patch = 0
        s2 = sy * sy + sx * sx;
    }
    kc[idx] = pw0 * __expf(-0.5f * s1) + pw1 * __expf(-0.5f * s2);
}

// ---------------- initial softmax(21)+4x4 pool -> transposed qt[b*HWP+p][24] ----------------
__global__ __launch_bounds__(256) void k_softmax_pool(const float* __restrict__ logq,
                                                      float* __restrict__ qt) {
    int t = blockIdx.x * 256 + threadIdx.x;     // 0..524287
    int sub = t & 15;
    int pp = t >> 4;                             // 0..32767 (incl b)
    int px = pp & 127, py = (pp >> 7) & 127, b = pp >> 14;
    int r = sub >> 2, i2 = sub & 3;
    int pix = ((4 * py + r) << 9) + 4 * px + i2;
    const float* sp = logq + (((size_t)(b * NCH)) << 18);

    float v[NCH];
#pragma unroll
    for (int c = 0; c < NCH; ++c) v[c] = sp[((size_t)c << 18) + pix];
    float m = v[0];
#pragma unroll
    for (int c = 1; c < NCH; ++c) m = fmaxf(m, v[c]);
    float s = 0.f;
#pragma unroll
    for (int c = 0; c < NCH; ++c) { v[c] = __expf(v[c] - m); s += v[c]; }
    float inv = 1.0f / s;
    float sum[NCH];
#pragma unroll
    for (int c = 0; c < NCH; ++c) {
        float q = v[c] * inv;
        q += __shfl_xor(q, 1, 16);
        q += __shfl_xor(q, 2, 16);
        q += __shfl_xor(q, 4, 16);
        q += __shfl_xor(q, 8, 16);
        sum[c] = q * 0.0625f;
    }
    if (sub == 0) {
        float* qrow = qt + (size_t)pp * QSTR;
#pragma unroll
        for (int c = 0; c < NCH; ++c) qrow[c] = sum[c];
    }
}

// ---------------- pac: thread per (cgroup-of-6, b, pixel); kc read 4x, Q rows contiguous ----------------
__global__ __launch_bounds__(256) void k_pac(const float* __restrict__ qt,
                                             const float* __restrict__ kc,
                                             float* __restrict__ msgc) {
    int idx = blockIdx.x * 256 + threadIdx.x;   // 0..131071
    int p = idx & (HWP - 1);
    int b = (idx >> 14) & 1;
    int g = idx >> 15;                           // 0..3
    int c0 = g * 6;                              // 0,6,12,18 (group 3: channels 18..20)
    int px = p & 127, py = p >> 7;
    float a0 = 0.f, a1 = 0.f, a2 = 0.f, a3 = 0.f, a4 = 0.f, a5 = 0.f;
    const float* kcb = kc + (((size_t)b * KK) << 14) + p;
    const float* qtb = qt + ((size_t)(b << 14)) * QSTR + c0;
    for (int dy = 0; dy < KS; ++dy) {
        int ny = py + dy - KPAD;
        if ((unsigned)ny >= 128u) continue;
#pragma unroll
        for (int dx = 0; dx < KS; ++dx) {
            int nx = px + dx - KPAD;
            if ((unsigned)nx >= 128u) continue;
            float k = kcb[((size_t)(dy * KS + dx)) << 14];
            const float* qr = qtb + (size_t)((ny << 7) + nx) * QSTR;
            float2 qa = *(const float2*)(qr);
            float2 qb2 = *(const float2*)(qr + 2);
            float2 qc = *(const float2*)(qr + 4);
            a0 += k * qa.x;  a1 += k * qa.y;
            a2 += k * qb2.x; a3 += k * qb2.y;
            a4 += k * qc.x;  a5 += k * qc.y;
        }
    }
    float* outp = msgc + (((size_t)(b * NCH + c0)) << 14) + p;
    outp[0] = a0;
    outp[(size_t)1 << 14] = a1;
    outp[(size_t)2 << 14] = a2;
    if (g < 3) {
        outp[(size_t)3 << 14] = a3;
        outp[(size_t)4 << 14] = a4;
        outp[(size_t)5 << 14] = a5;
    }
}

// ---------------- fused: out = uw*unary + up4(msg); qt = pool4(softmax(out)) ----------------
__global__ __launch_bounds__(256) void k_step(const float* __restrict__ unary,
                                              const float* __restrict__ msgc,
                                              const float* __restrict__ uwp,
                                              float* __restrict__ out,
                                              float* __restrict__ qt) {
    int t = blockIdx.x * 256 + threadIdx.x;     // 0..524287
    int sub = t & 15;
    int pp = t >> 4;
    int px = pp & 127, py = (pp >> 7) & 127, b = pp >> 14;
    int r = sub >> 2, i2 = sub & 3;
    int y = 4 * py + r, x = 4 * px + i2;
    int pix = (y << 9) + x;
    float uw = uwp[0];

    float syf = fminf(fmaxf(y * 0.25f - 0.375f, 0.0f), 127.0f);
    int y0 = (int)syf; float fy = syf - y0; int y1 = min(y0 + 1, 127);
    float sxf = fminf(fmaxf(x * 0.25f - 0.375f, 0.0f), 127.0f);
    int x0 = (int)sxf; float fx = sxf - x0; int x1 = min(x0 + 1, 127);
    int o00 = (y0 << 7) + x0, o01 = (y0 << 7) + x1;
    int o10 = (y1 << 7) + x0, o11 = (y1 << 7) + x1;

    const float* up = unary + (((size_t)(b * NCH)) << 18) + pix;
    const float* mp = msgc + (((size_t)(b * NCH)) << 14);
    float* op = out + (((size_t)(b * NCH)) << 18) + pix;

    float v[NCH];
#pragma unroll
    for (int c = 0; c < NCH; ++c) {
        float v00 = mp[o00], v01 = mp[o01], v10 = mp[o10], v11 = mp[o11];
        float a = v00 + (v10 - v00) * fy;
        float bb = v01 + (v11 - v01) * fy;
        float val = a + (bb - a) * fx;
        float ov = uw * up[(size_t)c << 18] + val;
        op[(size_t)c << 18] = ov;
        v[c] = ov;
        mp += HWP;
    }
    float m = v[0];
#pragma unroll
    for (int c = 1; c < NCH; ++c) m = fmaxf(m, v[c]);
    float ssum = 0.f;
#pragma unroll
    for (int c = 0; c < NCH; ++c) { v[c] = __expf(v[c] - m); ssum += v[c]; }
    float inv = 1.0f / ssum;
    float sum[NCH];
#pragma unroll
    for (int c = 0; c < NCH; ++c) {
        float qv = v[c] * inv;
        qv += __shfl_xor(qv, 1, 16);
        qv += __shfl_xor(qv, 2, 16);
        qv += __shfl_xor(qv, 4, 16);
        qv += __shfl_xor(qv, 8, 16);
        sum[c] = qv * 0.0625f;
    }
    if (sub == 0) {
        float* qrow = qt + (size_t)pp * QSTR;
#pragma unroll
        for (int c = 0; c < NCH; ++c) qrow[c] = sum[c];
    }
}

// ---------------- final step: out = uw*unary + up4(msg) (no softmax needed) ----------------
__global__ __launch_bounds__(256) void k_upcombine(const float* __restrict__ unary,
                                                   const float* __restrict__ msgc,
                                                   const float* __restrict__ uwp,
                                                   float* __restrict__ out) {
    int idx = blockIdx.x * 256 + threadIdx.x;   // 0..11010047 [b][21][512][512]
    float uw = uwp[0];
    int x = idx & 511, y = (idx >> 9) & 511;
    int t = idx >> 18;

    float syf = fminf(fmaxf(y * 0.25f - 0.375f, 0.0f), 127.0f);
    int y0 = (int)syf; float fy = syf - y0; int y1 = min(y0 + 1, 127);
    float sxf = fminf(fmaxf(x * 0.25f - 0.375f, 0.0f), 127.0f);
    int x0 = (int)sxf; float fx = sxf - x0; int x1 = min(x0 + 1, 127);

    const float* mp = msgc + (((size_t)t) << 14);
    float v00 = mp[(y0 << 7) + x0];
    float v01 = mp[(y0 << 7) + x1];
    float v10 = mp[(y1 << 7) + x0];
    float v11 = mp[(y1 << 7) + x1];
    float a = v00 + (v10 - v00) * fy;
    float bl = v01 + (v11 - v01) * fy;
    float val = a + (bl - a) * fx;

    out[idx] = uw * unary[idx] + val;
}

extern "C" void kernel_launch(void* const* d_in, const int* in_sizes, int n_in,
                              void* d_out, int out_size, void* d_ws, size_t ws_size,
                              hipStream_t stream) {
    const float* x  = (const float*)d_in[0];
    const float* wb = (const float*)d_in[1];
    const float* bb = (const float*)d_in[2];
    const float* uw = (const float*)d_in[3];
    const float* pw = (const float*)d_in[4];
    float* out = (float*)d_out;

    // Workspace budget appears to be ~1.5x out_bytes = 66,060,288 B (round-2
    // 66.19 MB crashed, round-1 65.80 MB passed). Keep footprint at the
    // proven 65,798,144 B by aliasing prgb (setup-only) onto msgc.
    float* ws    = (float*)d_ws;
    float* unary = ws;                    // 11,010,048 floats
    float* kc    = unary + 11010048;      // 3,964,928
    float* qt    = kc + 3964928;          // 32768*24 = 786,432
    float* msgc  = qt + 786432;           // 688,128
    float* prgb  = msgc;                  // 98,304 (aliases msgc; dead after k_build_kc)

    k_conv<<<512, 256, 0, stream>>>(x, wb, bb, unary);
    k_pool_rgb<<<384, 256, 0, stream>>>(x, prgb);
    k_build_kc<<<15488, 256, 0, stream>>>(prgb, pw, kc);
    k_softmax_pool<<<2048, 256, 0, stream>>>(unary, qt);

    for (int s = 0; s < 5; ++s) {
        k_pac<<<512, 256, 0, stream>>>(qt, kc, msgc);
        if (s < 4)
            k_step<<<2048, 256, 0, stream>>>(unary, msgc, uw, out, qt);
        else
            k_upcombine<<<43008, 256, 0, stream>>>(unary, msgc, uw, out);
    }
}

// Round 4
// 323.633 us; speedup vs baseline: 2.0424x; 1.2734x over previous
//
#include <hip/hip_runtime.h>

// B=2, H=W=512, 21 classes, 11x11 window, 4x blur. H,W % 4 == 0 -> pad=(0,0),
// avg-pool is exact 4x4 mean, post-upsample crop is identity.
#define NCH 21
#define HWF (1 << 18)   // 512*512
#define HWP (1 << 14)   // 128*128
#define KS 11
#define KK 121
#define KPAD 5
// pac tiling
#define TW 32
#define TH 8
#define HALO 5
#define LW (TW + 2 * HALO)   // 42
#define LH (TH + 2 * HALO)   // 18
#define LPLANE (LW * LH)     // 756

// ---------------- unary = conv3x3(x,w)+b : thread = 4-px quad, all 21 outputs ----------------
__global__ __launch_bounds__(256) void k_conv(const float* __restrict__ x,
                                              const float* __restrict__ w,
                                              const float* __restrict__ bias,
                                              float* __restrict__ unary) {
    int idx = blockIdx.x * 256 + threadIdx.x;   // 0..131071  [b][512][128]
    int b = idx >> 16;
    int rem = idx & 65535;
    int y = rem >> 7;
    int xq = (rem & 127) << 2;                  // base x, multiple of 4

    float p[3][3][6];
#pragma unroll
    for (int ch = 0; ch < 3; ++ch) {
        const float* xp = x + (((size_t)(b * 3 + ch)) << 18);
#pragma unroll
        for (int r = 0; r < 3; ++r) {
            int yy = y + r - 1;
            if ((unsigned)yy >= 512u) {
#pragma unroll
                for (int j = 0; j < 6; ++j) p[ch][r][j] = 0.f;
            } else {
                const float* row = xp + (yy << 9);
                float4 v = *(const float4*)(row + xq);
                p[ch][r][1] = v.x; p[ch][r][2] = v.y; p[ch][r][3] = v.z; p[ch][r][4] = v.w;
                p[ch][r][0] = (xq > 0) ? row[xq - 1] : 0.f;
                p[ch][r][5] = (xq + 4 < 512) ? row[xq + 4] : 0.f;
            }
        }
    }
    for (int o = 0; o < NCH; ++o) {
        const float* wp = w + o * 27;
        float bz = bias[o];
        float a0 = bz, a1 = bz, a2 = bz, a3 = bz;
#pragma unroll
        for (int ch = 0; ch < 3; ++ch)
#pragma unroll
            for (int r = 0; r < 3; ++r) {
                float w0 = wp[ch * 9 + r * 3 + 0];
                float w1 = wp[ch * 9 + r * 3 + 1];
                float w2 = wp[ch * 9 + r * 3 + 2];
                const float* pr = p[ch][r];
                a0 += w0 * pr[0] + w1 * pr[1] + w2 * pr[2];
                a1 += w0 * pr[1] + w1 * pr[2] + w2 * pr[3];
                a2 += w0 * pr[2] + w1 * pr[3] + w2 * pr[4];
                a3 += w0 * pr[3] + w1 * pr[4] + w2 * pr[5];
            }
        float4 ov = make_float4(a0, a1, a2, a3);
        *(float4*)(unary + (((size_t)(b * NCH + o)) << 18) + (y << 9) + xq) = ov;
    }
}

// ---------------- pooled RGB ----------------
__global__ __launch_bounds__(256) void k_pool_rgb(const float* __restrict__ x,
                                                  float* __restrict__ prgb) {
    int idx = blockIdx.x * 256 + threadIdx.x;   // 0..98303  [b][3][128][128]
    int p = idx & (HWP - 1);
    int ch = (idx >> 14) % 3;
    int b = idx / (3 * HWP);
    int py = p >> 7, px = p & 127;
    const float* xp = x + (((size_t)(b * 3 + ch)) << 18);
    float s = 0.f;
#pragma unroll
    for (int r = 0; r < 4; ++r) {
        const float4 v = *(const float4*)(xp + (((4 * py + r) << 9) + 4 * px));
        s += v.x + v.y + v.z + v.w;
    }
    prgb[idx] = s * 0.0625f;
}

// ---------------- kc = pw0*exp(-.5 s_bil) + pw1*exp(-.5 s_spat), thread per (b,tap,pixel) ----------------
__global__ __launch_bounds__(256) void k_build_kc(const float* __restrict__ prgb,
                                                  const float* __restrict__ pw,
                                                  float* __restrict__ kc) {
    int idx = blockIdx.x * 256 + threadIdx.x;   // [b][j][p]
    int p = idx & (HWP - 1);
    int jj = idx >> 14;                          // 0..241
    int b = (jj >= KK) ? 1 : 0;
    int j = jj - KK * b;
    int dy = j / KS, dx = j - dy * KS;
    int py = p >> 7, px = p & 127;
    float pw0 = pw[0], pw1 = pw[1];

    const float inv13 = 1.0f / 13.0f;
    float fy = (4.f * py + 1.5f) * (1.0f / 80.0f);
    float fx = (4.f * px + 1.5f) * (1.0f / 80.0f);
    const float* pb = prgb + (size_t)b * 3 * HWP;
    float r0 = pb[p] * inv13;
    float g0 = pb[HWP + p] * inv13;
    float b0 = pb[2 * HWP + p] * inv13;
    float sy = (4.f * py + 1.5f) * (1.0f / 3.0f);
    float sx = (4.f * px + 1.5f) * (1.0f / 3.0f);

    int ny = py + dy - KPAD;
    int nx = px + dx - KPAD;
    float s1, s2;
    if ((unsigned)ny < 128u && (unsigned)nx < 128u) {
        int np = (ny << 7) + nx;
        float r2 = pb[np] * inv13;
        float g2 = pb[HWP + np] * inv13;
        float b2 = pb[2 * HWP + np] * inv13;
        float dya = fy - (4.f * ny + 1.5f) * (1.0f / 80.0f);
        float dxa = fx - (4.f * nx + 1.5f) * (1.0f / 80.0f);
        float dr = r0 - r2, dg = g0 - g2, db = b0 - b2;
        s1 = dya * dya + dxa * dxa + dr * dr + dg * dg + db * db;
        float dys = sy - (4.f * ny + 1.5f) * (1.0f / 3.0f);
        float dxs = sx - (4.f * nx + 1.5f) * (1.0f / 3.0f);
        s2 = dys * dys + dxs * dxs;
    } else {
        s1 = fy * fy + fx * fx + r0 * r0 + g0 * g0 + b0 * b0;  // patch = 0
        s2 = sy * sy + sx * sx;
    }
    kc[idx] = pw0 * __expf(-0.5f * s1) + pw1 * __expf(-0.5f * s2);
}

// ---------------- initial softmax(21)+4x4 pool -> qb planes [b][c][128][128] ----------------
__global__ __launch_bounds__(256) void k_softmax_pool(const float* __restrict__ logq,
                                                      float* __restrict__ qb) {
    int t = blockIdx.x * 256 + threadIdx.x;     // 0..524287
    int sub = t & 15;
    int pp = t >> 4;                             // 0..32767 (incl b)
    int px = pp & 127, py = (pp >> 7) & 127, b = pp >> 14;
    int r = sub >> 2, i2 = sub & 3;
    int pix = ((4 * py + r) << 9) + 4 * px + i2;
    const float* sp = logq + (((size_t)(b * NCH)) << 18);

    float v[NCH];
#pragma unroll
    for (int c = 0; c < NCH; ++c) v[c] = sp[((size_t)c << 18) + pix];
    float m = v[0];
#pragma unroll
    for (int c = 1; c < NCH; ++c) m = fmaxf(m, v[c]);
    float s = 0.f;
#pragma unroll
    for (int c = 0; c < NCH; ++c) { v[c] = __expf(v[c] - m); s += v[c]; }
    float inv = 1.0f / s;
#pragma unroll
    for (int c = 0; c < NCH; ++c) {
        float q = v[c] * inv;
        q += __shfl_xor(q, 1, 16);
        q += __shfl_xor(q, 2, 16);
        q += __shfl_xor(q, 4, 16);
        q += __shfl_xor(q, 8, 16);
        if (sub == 0) qb[(((size_t)(b * NCH + c)) << 14) + (py << 7) + px] = q * 0.0625f;
    }
}

// ---------------- pac: LDS-staged 11x11 stencil; WG = 32x8 tile x 6-channel group ----------------
__global__ __launch_bounds__(256) void k_pac(const float* __restrict__ qb,
                                             const float* __restrict__ kc,
                                             float* __restrict__ msgc) {
    int tile = blockIdx.x & 63;                 // 4 x-tiles * 16 y-tiles
    int g = (blockIdx.x >> 6) & 3;              // channel group 0..3
    int b = blockIdx.x >> 8;                    // batch
    int c0 = g * 6;
    int ncg = (g == 3) ? 3 : 6;
    int tx0 = (tile & 3) * TW;
    int ty0 = (tile >> 2) * TH;

    __shared__ float lq[6 * LPLANE];            // 18144 B

    const float* qbase = qb + (((size_t)(b * NCH + c0)) << 14);
    for (int i = threadIdx.x; i < 6 * LPLANE; i += 256) {
        int ch = i / LPLANE;
        int rem = i - ch * LPLANE;
        int ly = rem / LW, lx = rem - ly * LW;
        int gy = ty0 + ly - HALO, gx = tx0 + lx - HALO;
        float v = 0.f;
        if (ch < ncg && (unsigned)gy < 128u && (unsigned)gx < 128u)
            v = qbase[((size_t)ch << 14) + (gy << 7) + gx];
        lq[i] = v;
    }
    __syncthreads();

    int tx = threadIdx.x & 31, ty = threadIdx.x >> 5;
    int p = ((ty0 + ty) << 7) + (tx0 + tx);
    const float* kcb = kc + (((size_t)b * KK) << 14) + p;
    float a0 = 0.f, a1 = 0.f, a2 = 0.f, a3 = 0.f, a4 = 0.f, a5 = 0.f;
    for (int dy = 0; dy < KS; ++dy) {
        const float* lrow = lq + (ty + dy) * LW + tx;
        const float* kcrow = kcb + (((size_t)(dy * KS)) << 14);
#pragma unroll
        for (int dx = 0; dx < KS; ++dx) {
            float k = kcrow[((size_t)dx) << 14];
            const float* lp = lrow + dx;
            a0 += k * lp[0 * LPLANE];
            a1 += k * lp[1 * LPLANE];
            a2 += k * lp[2 * LPLANE];
            a3 += k * lp[3 * LPLANE];
            a4 += k * lp[4 * LPLANE];
            a5 += k * lp[5 * LPLANE];
        }
    }
    float* outp = msgc + (((size_t)(b * NCH + c0)) << 14) + p;
    outp[0] = a0;
    outp[(size_t)1 << 14] = a1;
    outp[(size_t)2 << 14] = a2;
    if (ncg == 6) {
        outp[(size_t)3 << 14] = a3;
        outp[(size_t)4 << 14] = a4;
        outp[(size_t)5 << 14] = a5;
    }
}

// ---------------- fused (steps 0..3): logq = uw*unary + up4(msg) [NOT stored]; qb = pool4(softmax(logq)) ----------------
__global__ __launch_bounds__(256) void k_step(const float* __restrict__ unary,
                                              const float* __restrict__ msgc,
                                              const float* __restrict__ uwp,
                                              float* __restrict__ qb) {
    int t = blockIdx.x * 256 + threadIdx.x;     // 0..524287
    int sub = t & 15;
    int pp = t >> 4;
    int px = pp & 127, py = (pp >> 7) & 127, b = pp >> 14;
    int r = sub >> 2, i2 = sub & 3;
    int y = 4 * py + r, x = 4 * px + i2;
    int pix = (y << 9) + x;
    float uw = uwp[0];

    float syf = fminf(fmaxf(y * 0.25f - 0.375f, 0.0f), 127.0f);
    int y0 = (int)syf; float fy = syf - y0; int y1 = min(y0 + 1, 127);
    float sxf = fminf(fmaxf(x * 0.25f - 0.375f, 0.0f), 127.0f);
    int x0 = (int)sxf; float fx = sxf - x0; int x1 = min(x0 + 1, 127);
    int o00 = (y0 << 7) + x0, o01 = (y0 << 7) + x1;
    int o10 = (y1 << 7) + x0, o11 = (y1 << 7) + x1;

    const float* up = unary + (((size_t)(b * NCH)) << 18) + pix;
    const float* mp = msgc + (((size_t)(b * NCH)) << 14);

    float v[NCH];
#pragma unroll
    for (int c = 0; c < NCH; ++c) {
        float v00 = mp[o00], v01 = mp[o01], v10 = mp[o10], v11 = mp[o11];
        float a = v00 + (v10 - v00) * fy;
        float bb = v01 + (v11 - v01) * fy;
        float val = a + (bb - a) * fx;
        v[c] = uw * up[(size_t)c << 18] + val;
        mp += HWP;
    }
    float m = v[0];
#pragma unroll
    for (int c = 1; c < NCH; ++c) m = fmaxf(m, v[c]);
    float ssum = 0.f;
#pragma unroll
    for (int c = 0; c < NCH; ++c) { v[c] = __expf(v[c] - m); ssum += v[c]; }
    float inv = 1.0f / ssum;
#pragma unroll
    for (int c = 0; c < NCH; ++c) {
        float qv = v[c] * inv;
        qv += __shfl_xor(qv, 1, 16);
        qv += __shfl_xor(qv, 2, 16);
        qv += __shfl_xor(qv, 4, 16);
        qv += __shfl_xor(qv, 8, 16);
        if (sub == 0) qb[(((size_t)(b * NCH + c)) << 14) + (py << 7) + px] = qv * 0.0625f;
    }
}

// ---------------- final step: out = uw*unary + up4(msg) ----------------
__global__ __launch_bounds__(256) void k_upcombine(const float* __restrict__ unary,
                                                   const float* __restrict__ msgc,
                                                   const float* __restrict__ uwp,
                                                   float* __restrict__ out) {
    int idx = blockIdx.x * 256 + threadIdx.x;   // 0..11010047 [b][21][512][512]
    float uw = uwp[0];
    int x = idx & 511, y = (idx >> 9) & 511;
    int t = idx >> 18;

    float syf = fminf(fmaxf(y * 0.25f - 0.375f, 0.0f), 127.0f);
    int y0 = (int)syf; float fy = syf - y0; int y1 = min(y0 + 1, 127);
    float sxf = fminf(fmaxf(x * 0.25f - 0.375f, 0.0f), 127.0f);
    int x0 = (int)sxf; float fx = sxf - x0; int x1 = min(x0 + 1, 127);

    const float* mp = msgc + (((size_t)t) << 14);
    float v00 = mp[(y0 << 7) + x0];
    float v01 = mp[(y0 << 7) + x1];
    float v10 = mp[(y1 << 7) + x0];
    float v11 = mp[(y1 << 7) + x1];
    float a = v00 + (v10 - v00) * fy;
    float bl = v01 + (v11 - v01) * fy;
    float val = a + (bl - a) * fx;

    out[idx] = uw * unary[idx] + val;
}

extern "C" void kernel_launch(void* const* d_in, const int* in_sizes, int n_in,
                              void* d_out, int out_size, void* d_ws, size_t ws_size,
                              hipStream_t stream) {
    const float* x  = (const float*)d_in[0];
    const float* wb = (const float*)d_in[1];
    const float* bb = (const float*)d_in[2];
    const float* uw = (const float*)d_in[3];
    const float* pw = (const float*)d_in[4];
    float* out = (float*)d_out;

    // Footprint 65.4 MB (< proven 65.8 MB ceiling). prgb aliases msgc
    // (dead after k_build_kc; msgc first written by step-0 k_pac).
    float* ws    = (float*)d_ws;
    float* unary = ws;                    // 11,010,048 floats
    float* kc    = unary + 11010048;      // 3,964,928
    float* qb    = kc + 3964928;          // 688,128
    float* msgc  = qb + 688128;           // 688,128
    float* prgb  = msgc;                  // 98,304 (alias)

    k_conv<<<512, 256, 0, stream>>>(x, wb, bb, unary);
    k_pool_rgb<<<384, 256, 0, stream>>>(x, prgb);
    k_build_kc<<<15488, 256, 0, stream>>>(prgb, pw, kc);
    k_softmax_pool<<<2048, 256, 0, stream>>>(unary, qb);

    for (int s = 0; s < 5; ++s) {
        k_pac<<<512, 256, 0, stream>>>(qb, kc, msgc);
        if (s < 4)
            k_step<<<2048, 256, 0, stream>>>(unary, msgc, uw, qb);
        else
            k_upcombine<<<43008, 256, 0, stream>>>(unary, msgc, uw, out);
    }
}